// Round 9
// baseline (453.040 us; speedup 1.0000x reference)
//
#include <hip/hip_runtime.h>
#include <hip/hip_bf16.h>

typedef __hip_bfloat16 bf16;
typedef __attribute__((ext_vector_type(8))) short short8;
typedef __attribute__((ext_vector_type(4))) float f32x4;

#define NN 4096
#define L2E 1.4426950408889634f

// wave-shuffle block sum (256 threads)
__device__ inline float br_sum(float v, float* sd){
  #pragma unroll
  for(int s=32; s>0; s>>=1) v += __shfl_down(v, s, 64);
  int t = threadIdx.x;
  if ((t & 63) == 0) sd[t >> 6] = v;
  __syncthreads();
  float r = (sd[0] + sd[1]) + (sd[2] + sd[3]);
  __syncthreads();
  return r;
}

// async global->LDS, 16B per lane; lds base wave-uniform (HW adds lane*16)
__device__ inline void gl2lds(const bf16* g, unsigned int* lds){
  __builtin_amdgcn_global_load_lds(
      (const __attribute__((address_space(1))) unsigned int*)g,
      (__attribute__((address_space(3))) unsigned int*)lds, 16, 0, 0);
}

template<int N> __device__ inline void waitvm(){
  if constexpr (N==0)       asm volatile("s_waitcnt vmcnt(0)" ::: "memory");
  else if constexpr (N==4)  asm volatile("s_waitcnt vmcnt(4)" ::: "memory");
  else if constexpr (N==6)  asm volatile("s_waitcnt vmcnt(6)" ::: "memory");
  else if constexpr (N==8)  asm volatile("s_waitcnt vmcnt(8)" ::: "memory");
  else if constexpr (N==12) asm volatile("s_waitcnt vmcnt(12)" ::: "memory");
  else if constexpr (N==18) asm volatile("s_waitcnt vmcnt(18)" ::: "memory");
  else if constexpr (N==24) asm volatile("s_waitcnt vmcnt(24)" ::: "memory");
}
__device__ inline void pipe_barrier(){
  __builtin_amdgcn_s_barrier();
  asm volatile("" ::: "memory");
}

// ---------------------------------------------------------------------------
// fused prep:
//   blocks 0..4095    : one df row -> bf16 convert + logits2 dot (df read ONCE)
//   blocks 4096..5503 : weight transposes
//   blocks 5504..5519 : zero el1/er1 (SA) and el2/er2 (SB2)
// ---------------------------------------------------------------------------
__global__ __launch_bounds__(256)
void prep_all_k(const float* __restrict__ df, const float* __restrict__ W1,
                const float* __restrict__ W2, const float* __restrict__ lw,
                bf16* __restrict__ dfb, bf16* __restrict__ W1tb,
                bf16* __restrict__ W2tb, bf16* __restrict__ lwcat,
                const float* __restrict__ c2w, const float* __restrict__ c2b,
                float* __restrict__ out2,
                float* __restrict__ SA, float* __restrict__ SB2)
{
  int b = blockIdx.x, t = threadIdx.x;
  if (b < 4096){                        // row: convert + logits2
    __shared__ float sd4[4];
    int n = b, k0 = t*8;
    size_t i = (size_t)n*2048 + k0;
    f32x4 v0 = *(const f32x4*)(df + i);
    f32x4 v1 = *(const f32x4*)(df + i + 4);
    short8 s;
    float acc[10] = {};
    #pragma unroll
    for(int q=0;q<4;q++){
      bf16 h0 = __float2bfloat16(v0[q]);
      bf16 h1 = __float2bfloat16(v1[q]);
      s[q]   = *(short*)&h0;
      s[4+q] = *(short*)&h1;
      #pragma unroll
      for(int c=0;c<10;c++){
        acc[c] += v0[q]*c2w[(k0+q)*10 + c] + v1[q]*c2w[(k0+4+q)*10 + c];
      }
    }
    *(short8*)(dfb + i) = s;
    #pragma unroll
    for(int c=0;c<10;c++){
      float r = br_sum(acc[c], sd4);
      if(t==0) out2[n*10 + c] = r + c2b[c];
    }
    return;
  }
  if (b >= 5504){                       // zero el/er accumulators
    int r = (b - 5504)*256 + t;         // 0..4095
    SA[r] = 0.f; SA[r + 4096] = 0.f;               // el1, er1
    #pragma unroll
    for(int q=0;q<4;q++) SB2[r + q*4096] = 0.f;    // el2[2N], er2[2N]
    return;
  }
  b -= 4096;
  const float* src; bf16* dst; int rb, cb, dstld; bool dup=false;
  if (b < 512){            src=W1; dst=W1tb;  rb=(b>>4)<<6; cb=(b&15)<<6; dstld=2048; }
  else if (b < 768){ b-=512; src=W2; dst=W2tb; rb=(b>>4)<<6; cb=(b&15)<<6; dstld=1024; }
  else { b-=768; src=lw; dst=lwcat; rb=(b>>4)<<6; cb=(b&15)<<6; dstld=3072; dup=(rb>=2048); }
  __shared__ bf16 tile[64][65];
  #pragma unroll
  for(int i=0;i<16;i++){
    int lin=i*256+t, tr=lin>>6, tc=lin&63;
    tile[tr][tc] = __float2bfloat16(src[(size_t)(rb+tr)*1024 + cb+tc]);
  }
  __syncthreads();
  #pragma unroll
  for(int i=0;i<16;i++){
    int lin=i*256+t, tc=lin>>6, tr=lin&63;
    bf16 v = tile[tr][tc];
    dst[(size_t)(cb+tc)*dstld + rb+tr] = v;
    if(dup) dst[(size_t)(cb+tc)*dstld + rb+tr + 512] = v;
  }
}

// ---------------------------------------------------------------------------
// adjacency body (unchanged; swizzled, 3-buffer 2-ahead)
// ---------------------------------------------------------------------------
__device__ __forceinline__
void adj_body(const bf16* __restrict__ A, unsigned int* __restrict__ Cm,
              unsigned int* SH, int idx)
{
  unsigned int* As = SH;
  unsigned int* Bs = SH + 6144;
  const int tid = threadIdx.x;
  int by = (int)((65.0f - sqrtf(4225.0f - 8.0f*(float)idx)) * 0.5f);
  while ((by+1)*(65-(by+1))/2 <= idx) by++;
  while (by*(65-by)/2 > idx) by--;
  int bx = by + (idx - by*(65-by)/2);
  const int bm = by*128, bn = bx*128;
  const int lane = tid&63, wid = tid>>6;
  const int wr = (wid>>1)*64, wc = (wid&1)*64;
  const int quad = lane>>4, mr = lane&15;
  const int L4 = lane>>2;
  const int lsw = (lane&3) ^ ((lane>>3)&3);
  const int qsw4 = ((quad ^ ((mr>>1)&3)) << 2);

  f32x4 acc[4][4];
  #pragma unroll
  for(int i=0;i<4;i++)
    #pragma unroll
    for(int j=0;j<4;j++) acc[i][j] = (f32x4){0.f,0.f,0.f,0.f};

  auto stage = [&](int kb, int p){
    #pragma unroll
    for(int c2=0; c2<2; c2++){
      int row = (wid*2+c2)*16 + L4;
      gl2lds(A + (size_t)(bm+row)*2048 + kb + lsw*8, &As[p*2048 + (wid*2+c2)*256]);
      gl2lds(A + (size_t)(bn+row)*2048 + kb + lsw*8, &Bs[p*2048 + (wid*2+c2)*256]);
    }
  };
  auto compute = [&](int p){
    short8 af[4], bfr[4];
    #pragma unroll
    for(int i=0;i<4;i++)  af[i]  = *(const short8*)&As[p*2048 + (wr + i*16 + mr)*16 + qsw4];
    #pragma unroll
    for(int j=0;j<4;j++)  bfr[j] = *(const short8*)&Bs[p*2048 + (wc + j*16 + mr)*16 + qsw4];
    #pragma unroll
    for(int i=0;i<4;i++)
      #pragma unroll
      for(int j=0;j<4;j++)
        acc[i][j] = __builtin_amdgcn_mfma_f32_16x16x32_bf16(af[i], bfr[j], acc[i][j], 0,0,0);
  };

  stage(0,0); stage(32,1);
  int p = 0;
  #pragma unroll 1
  for(int it=0; it<63; it++){
    waitvm<4>();
    pipe_barrier();
    if (it+2 < 64) stage(32*(it+2), p==0?2:p-1);
    compute(p);
    p = (p==2)?0:p+1;
  }
  waitvm<0>();
  pipe_barrier();
  compute(p);

  #pragma unroll
  for(int i=0;i<4;i++){
    #pragma unroll
    for(int j=0;j<4;j++){
      int cbase = bn + wc + j*16;
      unsigned long long b[4];
      #pragma unroll
      for(int reg=0; reg<4; reg++){
        float v = acc[i][j][reg];
        unsigned long long msk = __ballot(v > 0.f);
        b[reg] = msk;
        if (mr == 0){
          int r = bm + wr + i*16 + quad*4 + reg;
          unsigned int x = (unsigned int)(msk >> (quad*16)) & 0xFFFFu;
          x = (x | (x << 8)) & 0x00FF00FFu;
          x = (x | (x << 4)) & 0x0F0F0F0Fu;
          x = (x | (x << 2)) & 0x33333333u;
          x = (x | (x << 1)) & 0x55555555u;
          if (r >= cbase && r < cbase + 16) x += 1u << (2*(r - cbase));
          Cm[(size_t)r*256 + (cbase>>4)] = x;
        }
      }
      if (bx > by){
        unsigned int x = 0;
        #pragma unroll
        for(int reg=0; reg<4; reg++){
          unsigned long long t = (b[reg] >> mr) & 0x0001000100010001ULL;
          unsigned int f = (unsigned int)((t | (t>>15) | (t>>30) | (t>>45)) & 0xFULL);
          x |= ((f&1u) | ((f&2u)<<7) | ((f&4u)<<14) | ((f&8u)<<21)) << (2*reg);
        }
        if (quad == 0){
          int c = cbase + mr;
          Cm[(size_t)c*256 + ((bm + wr + i*16)>>4)] = x;
        }
      }
    }
  }
}

// ---------------------------------------------------------------------------
// GEMM body: C = A @ Bt^T, 128 x TN tile, NS-deep pipeline, swizzled LDS.
// EPI: 0 none | 1 relu->bf16 | 2 bf16 | 4 +bias+leaky f32
// EL:  0 none | 1/2 fused el/er partial rows via atomics (EL==2: head = bn>>9)
// ---------------------------------------------------------------------------
template<int EPI, int TN, int DUALA, int K, int LDA, int LDBT, int LDC,
         int K1, int LDA2, int WT, int NS, int EL>
__device__ __forceinline__
void gemm_body(const bf16* __restrict__ Ag, const bf16* __restrict__ Bt,
               void* __restrict__ Cv, const float* __restrict__ bias,
               const bf16* __restrict__ Ag2, bf16* __restrict__ Ct,
               const float* __restrict__ eA, const float* __restrict__ eB,
               float* __restrict__ eX, float* __restrict__ eY,
               unsigned int* SH, int bid)
{
  constexpr int NJ  = TN/32;
  constexpr int D   = 2 + TN/64;
  constexpr int NIT = K/32;
  unsigned int* As = SH;
  unsigned int* Bs = SH + NS*2048;
  const int tid = threadIdx.x;
  const int by = 4*(bid&7) + ((bid>>3)&3);
  const int bx = bid>>5;
  const int bm = by*128, bn = bx*TN;
  const int lane = tid&63, wid = tid>>6;
  const int wr = (wid>>1)*64, wc = (wid&1)*(TN/2);
  const int quad = lane>>4, mr = lane&15;
  const int L4 = lane>>2;
  const int lsw = (lane&3) ^ ((lane>>3)&3);
  const int qsw4 = ((quad ^ ((mr>>1)&3)) << 2);

  f32x4 acc[4][NJ];
  #pragma unroll
  for(int i=0;i<4;i++)
    #pragma unroll
    for(int j=0;j<NJ;j++) acc[i][j] = (f32x4){0.f,0.f,0.f,0.f};

  auto stage = [&](int kb, int p){
    #pragma unroll
    for(int c2=0; c2<2; c2++){
      int row = (wid*2+c2)*16 + L4;
      const bf16* ap;
      if (DUALA && kb >= K1) ap = Ag2 + (size_t)(bm+row)*LDA2 + (kb-K1);
      else                   ap = Ag  + (size_t)(bm+row)*LDA  + kb;
      gl2lds(ap + lsw*8, &As[p*2048 + (wid*2+c2)*256]);
    }
    #pragma unroll
    for(int c2=0; c2<TN/64; c2++){
      int row = (wid*(TN/64)+c2)*16 + L4;
      gl2lds(Bt + (size_t)(bn+row)*LDBT + kb + lsw*8,
             &Bs[p*(TN*16) + (wid*(TN/64)+c2)*256]);
    }
  };
  auto compute = [&](int p){
    short8 af[4], bfr[NJ];
    #pragma unroll
    for(int i=0;i<4;i++)
      af[i]  = *(const short8*)&As[p*2048 + (wr + i*16 + mr)*16 + qsw4];
    #pragma unroll
    for(int j=0;j<NJ;j++)
      bfr[j] = *(const short8*)&Bs[p*(TN*16) + (wc + j*16 + mr)*16 + qsw4];
    #pragma unroll
    for(int i=0;i<4;i++)
      #pragma unroll
      for(int j=0;j<NJ;j++)
        acc[i][j] = __builtin_amdgcn_mfma_f32_16x16x32_bf16(af[i], bfr[j], acc[i][j], 0,0,0);
  };

  #pragma unroll
  for(int s=0; s<NS-1; s++) stage(32*s, s);
  int p = 0;
  #pragma unroll 1
  for(int it=0; it<NIT-(NS-1); it++){
    waitvm<(NS-2)*D>();
    pipe_barrier();
    stage(32*(it+NS-1), (p+NS-1)&(NS-1));
    compute(p); p=(p+1)&(NS-1);
  }
  waitvm<0>(); pipe_barrier();
  #pragma unroll 1
  for(int r=0; r<NS-1; r++){ compute(p); p=(p+1)&(NS-1); }

  if (EPI==1 || EPI==2 || EPI==4){
    #pragma unroll
    for(int i=0;i<4;i++){
      #pragma unroll
      for(int j=0;j<NJ;j++){
        #pragma unroll
        for(int reg=0; reg<4; reg++){
          int r = bm + wr + i*16 + quad*4 + reg;
          int c = bn + wc + j*16 + mr;
          float v = acc[i][j][reg];
          if (EPI==1){ ((bf16*)Cv)[(size_t)r*LDC + c] = __float2bfloat16(fmaxf(v,0.f)); }
          if (EPI==2){ ((bf16*)Cv)[(size_t)r*LDC + c] = __float2bfloat16(v); }
          if (EPI==4){ float w = v + bias[c];
                       ((float*)Cv)[(size_t)r*LDC + c] = w > 0.f ? w : 0.01f*w; }
        }
      }
    }
  }

  if (EL){       // fused el/er partials (feat row . al/ar)
    float* elp = eX; float* erp = eY;
    if (EL==2){ int hh = bn >> 9; elp += hh*NN; erp += hh*NN; }
    #pragma unroll
    for(int i=0;i<4;i++){
      #pragma unroll
      for(int reg=0; reg<4; reg++){
        float pl = 0.f, pr = 0.f;
        #pragma unroll
        for(int j=0;j<NJ;j++){
          int c = bn + wc + j*16 + mr;
          float v = acc[i][j][reg];
          pl += v * eA[c];
          pr += v * eB[c];
        }
        #pragma unroll
        for(int s=1;s<16;s<<=1){ pl += __shfl_xor(pl, s); pr += __shfl_xor(pr, s); }
        if (mr == 0){
          int n = bm + wr + i*16 + quad*4 + reg;
          atomicAdd(&elp[n], pl*L2E);
          atomicAdd(&erp[n], pr*L2E);
        }
      }
    }
  }

  if (WT){   // transposed copy via padded LDS (stride 66 shorts), coalesced out
    __syncthreads();
    bf16* T = (bf16*)SH;
    #pragma unroll
    for(int i=0;i<4;i++)
      #pragma unroll
      for(int j=0;j<NJ;j++)
        #pragma unroll
        for(int reg=0; reg<4; reg++){
          int rl = wr + i*16 + quad*4 + reg;
          int cl = wc + j*16 + mr;
          T[rl*66 + cl] = __float2bfloat16(acc[i][j][reg]);
        }
    __syncthreads();
    #pragma unroll
    for(int w=0; w<TN/4; w++){
      int cl = wid*(TN/4) + w;
      unsigned int v = (unsigned int)(*(unsigned short*)&T[(2*lane)*66 + cl]) |
                       ((unsigned int)(*(unsigned short*)&T[(2*lane+1)*66 + cl]) << 16);
      *(unsigned int*)&Ct[(size_t)(bn+cl)*4096 + bm + 2*lane] = v;
    }
  }
}

// standalone GEMM kernel
template<int EPI, int TN, int DUALA, int K, int LDA, int LDBT, int LDC,
         int K1, int LDA2, int WT, int NS, int EL>
__global__ __launch_bounds__(256)
void gemm_k(const bf16* __restrict__ Ag, const bf16* __restrict__ Bt,
            void* __restrict__ Cv, const float* __restrict__ bias,
            const bf16* __restrict__ Ag2, bf16* __restrict__ Ct,
            const float* __restrict__ eA, const float* __restrict__ eB,
            float* __restrict__ eX, float* __restrict__ eY)
{
  __shared__ unsigned int SH[NS*2048 + NS*TN*16];
  gemm_body<EPI,TN,DUALA,K,LDA,LDBT,LDC,K1,LDA2,WT,NS,EL>(
      Ag, Bt, Cv, bias, Ag2, Ct, eA, eB, eX, eY, SH, blockIdx.x);
}

// merged dual-head aggregation: blocks 0..255 head0, 256..511 head1.
// TN=64 NS=4 = 48 KB LDS, 512 blocks -> 2 blk/CU co-residency (R3-proven).
__global__ __launch_bounds__(256)
void agg2_k(const bf16* __restrict__ P, const bf16* __restrict__ P2,
            const bf16* __restrict__ featT, bf16* __restrict__ x2cat)
{
  __shared__ unsigned int SH[4*2048 + 4*64*16];
  int b = blockIdx.x;
  const bf16* A = (b < 256) ? P : P2;
  const bf16* B = (b < 256) ? featT : featT + (size_t)512*4096;
  bf16* C = (b < 256) ? x2cat : x2cat + 512;
  gemm_body<2,64,0,4096,4096,4096,1024,0,0,0,4,0>(
      A, B, C, nullptr, nullptr, nullptr, nullptr, nullptr, nullptr, nullptr,
      SH, b & 255);
}

// ---------------------------------------------------------------------------
// fused adjacency + feat1: blocks 0..527 adj tiles, 528..1039 feat1 GEMM
// (EPI=0: featT + fused el1/er1 only).
// ---------------------------------------------------------------------------
__global__ __launch_bounds__(256)
void adjfeat_k(const bf16* __restrict__ dfb, unsigned int* __restrict__ mult2,
               const bf16* __restrict__ W1tb, bf16* __restrict__ featT,
               const float* __restrict__ al1, const float* __restrict__ ar1,
               float* __restrict__ el1, float* __restrict__ er1)
{
  __shared__ unsigned int SH[12288];   // 48 KB union
  int b = blockIdx.x;
  if (b < 528){
    adj_body(dfb, mult2, SH, b);
  } else {
    gemm_body<0,64,0,2048,2048,2048,1024,0,0,1,4,1>(
        dfb, W1tb, nullptr, nullptr, nullptr, featT, al1, ar1, el1, er1,
        SH, b-528);
  }
}

// ---------------------------------------------------------------------------
// fused column softmax stats + alpha materialization (log2 space).
// ---------------------------------------------------------------------------
__global__ __launch_bounds__(256)
void colp_k(const float* __restrict__ el, const float* __restrict__ er,
            const unsigned int* __restrict__ mult2,
            float* __restrict__ cm, float* __restrict__ cinv,
            bf16* __restrict__ P, bf16* __restrict__ P2)
{
  __shared__ float sd[256];
  int d = blockIdx.x & 4095, hs = blockIdx.x >> 12, t = threadIdx.x;
  el += hs*NN; er += hs*NN; cm += hs*NN; cinv += hs*NN;
  float erd = er[d];
  unsigned int bits = mult2[(size_t)d*256 + t];
  float tv[16];
  float mx = -1e30f;
  const float* ep = el + t*16;
  #pragma unroll
  for(int h=0; h<4; h++){
    f32x4 ev = *(const f32x4*)(ep + h*4);
    #pragma unroll
    for(int q2=0;q2<4;q2++){
      int q = h*4 + q2;
      unsigned int mu = (bits >> (2*q)) & 3u;
      float x = ev[q2] + erd;
      x = fmaxf(x, 0.2f*x);
      if (mu == 2u) x += 1.0f;          // log2(2)
      tv[q] = mu ? x : -1e30f;
      mx = fmaxf(mx, tv[q]);
    }
  }
  #pragma unroll
  for(int s=32; s>0; s>>=1) mx = fmaxf(mx, __shfl_down(mx, s, 64));
  if ((t & 63) == 0) sd[t >> 6] = mx;
  __syncthreads();
  float M = fmaxf(fmaxf(sd[0], sd[1]), fmaxf(sd[2], sd[3]));
  __syncthreads();
  float sum = 0.f;
  #pragma unroll
  for(int q=0;q<16;q++) sum += (tv[q] > -1e29f) ? __builtin_exp2f(tv[q]-M) : 0.f;
  sum = br_sum(sum, sd);
  if(t==0){ cm[d] = M; cinv[d] = 1.f/sum; }
  bf16* Pd = (hs == 0) ? P : P2;
  if (Pd){
    float inv = 1.f/sum;
    unsigned int pk[8];
    #pragma unroll
    for(int h=0; h<4; h++){
      #pragma unroll
      for(int q2=0; q2<4; q2++){
        int q = h*4+q2;
        float v = (tv[q] > -1e29f) ? __builtin_exp2f(tv[q]-M)*inv : 0.f;
        bf16 hb = __float2bfloat16(v);
        unsigned short us = *(unsigned short*)&hb;
        if (q2 & 1) pk[h*2 + (q2>>1)] |= ((unsigned int)us << 16);
        else        pk[h*2 + (q2>>1)]  = (unsigned int)us;
      }
    }
    uint4* dst = (uint4*)(Pd + (size_t)d*4096 + t*16);
    dst[0] = *(uint4*)&pk[0];
    dst[1] = *(uint4*)&pk[4];
  }
}

// ---------------------------------------------------------------------------
// standalone alpha build (fallback path when workspace < 128 MB)
// ---------------------------------------------------------------------------
__global__ __launch_bounds__(256)
void pbuild_k(const float* __restrict__ el, const float* __restrict__ er,
              const float* __restrict__ cm, const float* __restrict__ cinv,
              const unsigned int* __restrict__ mult2, bf16* __restrict__ P)
{
  int d = blockIdx.x, t = threadIdx.x;
  const float erd = er[d], md = cm[d], invd = cinv[d];
  unsigned int bits = mult2[(size_t)d*256 + t];
  unsigned int pk[8];
  const float* ep = el + t*16;
  #pragma unroll
  for(int h=0; h<4; h++){
    f32x4 ev = *(const f32x4*)(ep + h*4);
    #pragma unroll
    for(int q2=0; q2<4; q2++){
      int q = h*4+q2;
      unsigned int mu = (bits >> (2*q)) & 3u;
      float x = ev[q2] + erd;
      x = fmaxf(x, 0.2f*x);
      float v = __builtin_exp2f(x + (mu>1u ? 1.0f : 0.0f) - md) * invd;
      v = mu ? v : 0.0f;
      bf16 hb = __float2bfloat16(v);
      unsigned short us = *(unsigned short*)&hb;
      if (q2 & 1) pk[h*2 + (q2>>1)] |= ((unsigned int)us << 16);
      else        pk[h*2 + (q2>>1)]  = (unsigned int)us;
    }
  }
  uint4* dst = (uint4*)(P + (size_t)d*4096 + t*16);
  dst[0] = *(uint4*)&pk[0];
  dst[1] = *(uint4*)&pk[4];
}

// ---------------------------------------------------------------------------
// classifier 1 (logits2 folded into prep_all_k); f32x4 loads
// ---------------------------------------------------------------------------
__global__ __launch_bounds__(256)
void cls2_k(const float* __restrict__ x3, const float* __restrict__ c1w,
            const float* __restrict__ c1b, float* __restrict__ out)
{
  __shared__ float sd[256];
  int n = blockIdx.x, t = threadIdx.x, k0 = t*4;
  f32x4 xv = *(const f32x4*)(x3 + (size_t)n*1024 + k0);
  float acc[10] = {};
  #pragma unroll
  for(int q=0;q<4;q++){
    #pragma unroll
    for(int c=0;c<10;c++) acc[c] += xv[q] * c1w[(k0+q)*10 + c];
  }
  for(int c=0;c<10;c++){
    float r = br_sum(acc[c], sd);
    if(t==0) out[n*10 + c] = r + c1b[c];
  }
}

// ---------------------------------------------------------------------------
extern "C" void kernel_launch(void* const* d_in, const int* in_sizes, int n_in,
                              void* d_out, int out_size, void* d_ws, size_t ws_size,
                              hipStream_t stream) {
  (void)in_sizes; (void)n_in; (void)out_size;
  const float* df  = (const float*)d_in[0];
  const float* W1  = (const float*)d_in[1];
  const float* al1 = (const float*)d_in[2];
  const float* ar1 = (const float*)d_in[3];
  const float* W2  = (const float*)d_in[4];
  const float* al2 = (const float*)d_in[5];
  const float* ar2 = (const float*)d_in[6];
  const float* lw  = (const float*)d_in[7];
  const float* lb  = (const float*)d_in[8];
  const float* c1w = (const float*)d_in[9];
  const float* c1b = (const float*)d_in[10];
  const float* c2w = (const float*)d_in[11];
  const float* c2b = (const float*)d_in[12];
  float* out = (float*)d_out;

  char* Wp = (char*)d_ws;
  bf16* W1tb  = (bf16*)(Wp);                                // 4 MB, dead after feat1
  bf16* W2tb  = (bf16*)(Wp + ( 4u<<20));                    // 2 MB
  bf16* lwcat = (bf16*)(Wp + ( 6u<<20));                    // 6 MB [1024][3072]
  unsigned int* mult2 = (unsigned int*)(Wp + (12u<<20));    // 4 MB packed adj
  bf16* dfb   = (bf16*)(Wp + (16u<<20));                    // 16 MB [4096][2048]
  float* SB2  = (float*)(Wp + (32u<<20));                   // el2/er2/m2/i2 (128 KB)
  float* x3   = (float*)(Wp + (32u<<20));                   // 16 MB (over SB2, written after)
  bf16* featT = (bf16*)(Wp + (48u<<20));                    // 8 MB [1024][4096]
  float* SA   = (float*)(Wp + (56u<<20));                   // el1/er1/m1/i1 (64 KB)
  bf16* x1b   = (bf16*)(Wp + (56u<<20));                    // 8 MB (over SA, after colp1)
  bf16* x2cat = (bf16*)(Wp + (56u<<20));                    // 8 MB (x1b dead)
  bf16* P     = (bf16*)(Wp + (64u<<20));                    // 32 MB alpha h0
  bf16* P2    = (bf16*)(Wp + (96u<<20));                    // 32 MB alpha h1 (if ws allows)
  const bool bigws = ws_size >= ((size_t)128 << 20);
  float *el1 = SA,        *er1 = SA + 4096;
  float *m1  = SA + 8192, *i1  = SA + 12288;
  float *el2 = SB2,           *er2 = SB2 + 8192;            // [2N] each
  float *m2  = SB2 + 16384,   *i2  = SB2 + 24576;

  // 0) prep: df convert + logits2, transposes, el/er zeroing
  prep_all_k<<<5520,256,0,stream>>>(df, W1, W2, lw, dfb, W1tb, W2tb, lwcat,
                                    c2w, c2b, out + NN*10, SA, SB2);

  // 1+2) adjacency (528) + feat1 GEMM (512): featT + fused el1/er1
  adjfeat_k<<<1040,256,0,stream>>>(dfb, mult2, W1tb, featT, al1, ar1, el1, er1);

  // 3) layer-1 stats + alpha (P)
  colp_k<<<4096,256,0,stream>>>(el1, er1, mult2, m1, i1, P, nullptr);

  // 4) x1 = relu(P @ feat1)  TN=64 NS=4, 512 blocks -> 2 blk/CU
  gemm_k<1,64,0,4096,4096,4096,1024,0,0,0,4,0><<<512,256,0,stream>>>(
      P, featT, x1b, nullptr, nullptr, nullptr, nullptr, nullptr, nullptr, nullptr);

  // 5) feat2: featT + fused el2/er2, TN=64 NS=4, 512 blocks -> 2 blk/CU
  gemm_k<0,64,0,1024,1024,1024,1024,0,0,1,4,2><<<512,256,0,stream>>>(
      x1b, W2tb, nullptr, nullptr, nullptr, featT, al2, ar2, el2, er2);

  // 6) layer-2 stats + alpha (P / P2)
  colp_k<<<8192,256,0,stream>>>(el2, er2, mult2, m2, i2, P, bigws ? P2 : nullptr);

  if (bigws){
    // both heads co-launched: 512 blocks TN=64 -> 2 blk/CU (R3 config)
    agg2_k<<<512,256,0,stream>>>(P, P2, featT, x2cat);
  } else {
    gemm_k<2,64,0,4096,4096,4096,1024,0,0,0,4,0><<<512,256,0,stream>>>(
        P, featT, x2cat, nullptr, nullptr, nullptr, nullptr, nullptr, nullptr, nullptr);
    pbuild_k<<<4096,256,0,stream>>>(el2+NN, er2+NN, m2+NN, i2+NN, mult2, P);
    gemm_k<2,64,0,4096,4096,4096,1024,0,0,0,4,0><<<512,256,0,stream>>>(
        P, featT + (size_t)512*4096, x2cat + 512, nullptr, nullptr, nullptr,
        nullptr, nullptr, nullptr, nullptr);
  }

  // 7) x3 = leaky([df | x2] @ lin1_w + b), dual-A K=3072, TN=64 NS=4, 512 blk
  gemm_k<4,64,1,3072,2048,3072,1024,2048,1024,0,4,0><<<512,256,0,stream>>>(
      dfb, lwcat, x3, lb, x2cat, nullptr, nullptr, nullptr, nullptr, nullptr);

  // 8) classifier 1 -> f32 out
  cls2_k<<<4096,256,0,stream>>>(x3, c1w, c1b, out);
}

// Round 10
// 433.247 us; speedup vs baseline: 1.0457x; 1.0457x over previous
//
#include <hip/hip_runtime.h>
#include <hip/hip_bf16.h>

typedef __hip_bfloat16 bf16;
typedef __attribute__((ext_vector_type(8))) short short8;
typedef __attribute__((ext_vector_type(4))) float f32x4;

#define NN 4096
#define L2E 1.4426950408889634f

// wave-shuffle block sum (256 threads)
__device__ inline float br_sum(float v, float* sd){
  #pragma unroll
  for(int s=32; s>0; s>>=1) v += __shfl_down(v, s, 64);
  int t = threadIdx.x;
  if ((t & 63) == 0) sd[t >> 6] = v;
  __syncthreads();
  float r = (sd[0] + sd[1]) + (sd[2] + sd[3]);
  __syncthreads();
  return r;
}

// async global->LDS, 16B per lane; lds base wave-uniform (HW adds lane*16)
__device__ inline void gl2lds(const bf16* g, unsigned int* lds){
  __builtin_amdgcn_global_load_lds(
      (const __attribute__((address_space(1))) unsigned int*)g,
      (__attribute__((address_space(3))) unsigned int*)lds, 16, 0, 0);
}

template<int N> __device__ inline void waitvm(){
  if constexpr (N==0)       asm volatile("s_waitcnt vmcnt(0)" ::: "memory");
  else if constexpr (N==4)  asm volatile("s_waitcnt vmcnt(4)" ::: "memory");
  else if constexpr (N==6)  asm volatile("s_waitcnt vmcnt(6)" ::: "memory");
  else if constexpr (N==8)  asm volatile("s_waitcnt vmcnt(8)" ::: "memory");
  else if constexpr (N==12) asm volatile("s_waitcnt vmcnt(12)" ::: "memory");
  else if constexpr (N==18) asm volatile("s_waitcnt vmcnt(18)" ::: "memory");
  else if constexpr (N==24) asm volatile("s_waitcnt vmcnt(24)" ::: "memory");
}
__device__ inline void pipe_barrier(){
  __builtin_amdgcn_s_barrier();
  asm volatile("" ::: "memory");
}

// ---------------------------------------------------------------------------
// fused prep:
//   blocks 0..4095    : one df row -> bf16 convert + logits2 dot (df read ONCE)
//   blocks 4096..5503 : weight transposes
//   blocks 5504..5519 : zero el1/er1 (SA) and el2/er2 (SB2)
// ---------------------------------------------------------------------------
__global__ __launch_bounds__(256)
void prep_all_k(const float* __restrict__ df, const float* __restrict__ W1,
                const float* __restrict__ W2, const float* __restrict__ lw,
                bf16* __restrict__ dfb, bf16* __restrict__ W1tb,
                bf16* __restrict__ W2tb, bf16* __restrict__ lwcat,
                const float* __restrict__ c2w, const float* __restrict__ c2b,
                float* __restrict__ out2,
                float* __restrict__ SA, float* __restrict__ SB2)
{
  int b = blockIdx.x, t = threadIdx.x;
  if (b < 4096){                        // row: convert + logits2
    __shared__ float sd4[4];
    int n = b, k0 = t*8;
    size_t i = (size_t)n*2048 + k0;
    f32x4 v0 = *(const f32x4*)(df + i);
    f32x4 v1 = *(const f32x4*)(df + i + 4);
    short8 s;
    float acc[10] = {};
    #pragma unroll
    for(int q=0;q<4;q++){
      bf16 h0 = __float2bfloat16(v0[q]);
      bf16 h1 = __float2bfloat16(v1[q]);
      s[q]   = *(short*)&h0;
      s[4+q] = *(short*)&h1;
      #pragma unroll
      for(int c=0;c<10;c++){
        acc[c] += v0[q]*c2w[(k0+q)*10 + c] + v1[q]*c2w[(k0+4+q)*10 + c];
      }
    }
    *(short8*)(dfb + i) = s;
    #pragma unroll
    for(int c=0;c<10;c++){
      float r = br_sum(acc[c], sd4);
      if(t==0) out2[n*10 + c] = r + c2b[c];
    }
    return;
  }
  if (b >= 5504){                       // zero el/er accumulators
    int r = (b - 5504)*256 + t;         // 0..4095
    SA[r] = 0.f; SA[r + 4096] = 0.f;               // el1, er1
    #pragma unroll
    for(int q=0;q<4;q++) SB2[r + q*4096] = 0.f;    // el2[2N], er2[2N]
    return;
  }
  b -= 4096;
  const float* src; bf16* dst; int rb, cb, dstld; bool dup=false;
  if (b < 512){            src=W1; dst=W1tb;  rb=(b>>4)<<6; cb=(b&15)<<6; dstld=2048; }
  else if (b < 768){ b-=512; src=W2; dst=W2tb; rb=(b>>4)<<6; cb=(b&15)<<6; dstld=1024; }
  else { b-=768; src=lw; dst=lwcat; rb=(b>>4)<<6; cb=(b&15)<<6; dstld=3072; dup=(rb>=2048); }
  __shared__ bf16 tile[64][65];
  #pragma unroll
  for(int i=0;i<16;i++){
    int lin=i*256+t, tr=lin>>6, tc=lin&63;
    tile[tr][tc] = __float2bfloat16(src[(size_t)(rb+tr)*1024 + cb+tc]);
  }
  __syncthreads();
  #pragma unroll
  for(int i=0;i<16;i++){
    int lin=i*256+t, tc=lin>>6, tr=lin&63;
    bf16 v = tile[tr][tc];
    dst[(size_t)(cb+tc)*dstld + rb+tr] = v;
    if(dup) dst[(size_t)(cb+tc)*dstld + rb+tr + 512] = v;
  }
}

// ---------------------------------------------------------------------------
// adjacency body (swizzled, 3-buffer 2-ahead)
// ---------------------------------------------------------------------------
__device__ __forceinline__
void adj_body(const bf16* __restrict__ A, unsigned int* __restrict__ Cm,
              unsigned int* SH, int idx)
{
  unsigned int* As = SH;
  unsigned int* Bs = SH + 6144;
  const int tid = threadIdx.x;
  int by = (int)((65.0f - sqrtf(4225.0f - 8.0f*(float)idx)) * 0.5f);
  while ((by+1)*(65-(by+1))/2 <= idx) by++;
  while (by*(65-by)/2 > idx) by--;
  int bx = by + (idx - by*(65-by)/2);
  const int bm = by*128, bn = bx*128;
  const int lane = tid&63, wid = tid>>6;
  const int wr = (wid>>1)*64, wc = (wid&1)*64;
  const int quad = lane>>4, mr = lane&15;
  const int L4 = lane>>2;
  const int lsw = (lane&3) ^ ((lane>>3)&3);
  const int qsw4 = ((quad ^ ((mr>>1)&3)) << 2);

  f32x4 acc[4][4];
  #pragma unroll
  for(int i=0;i<4;i++)
    #pragma unroll
    for(int j=0;j<4;j++) acc[i][j] = (f32x4){0.f,0.f,0.f,0.f};

  auto stage = [&](int kb, int p){
    #pragma unroll
    for(int c2=0; c2<2; c2++){
      int row = (wid*2+c2)*16 + L4;
      gl2lds(A + (size_t)(bm+row)*2048 + kb + lsw*8, &As[p*2048 + (wid*2+c2)*256]);
      gl2lds(A + (size_t)(bn+row)*2048 + kb + lsw*8, &Bs[p*2048 + (wid*2+c2)*256]);
    }
  };
  auto compute = [&](int p){
    short8 af[4], bfr[4];
    #pragma unroll
    for(int i=0;i<4;i++)  af[i]  = *(const short8*)&As[p*2048 + (wr + i*16 + mr)*16 + qsw4];
    #pragma unroll
    for(int j=0;j<4;j++)  bfr[j] = *(const short8*)&Bs[p*2048 + (wc + j*16 + mr)*16 + qsw4];
    #pragma unroll
    for(int i=0;i<4;i++)
      #pragma unroll
      for(int j=0;j<4;j++)
        acc[i][j] = __builtin_amdgcn_mfma_f32_16x16x32_bf16(af[i], bfr[j], acc[i][j], 0,0,0);
  };

  stage(0,0); stage(32,1);
  int p = 0;
  #pragma unroll 1
  for(int it=0; it<63; it++){
    waitvm<4>();
    pipe_barrier();
    if (it+2 < 64) stage(32*(it+2), p==0?2:p-1);
    compute(p);
    p = (p==2)?0:p+1;
  }
  waitvm<0>();
  pipe_barrier();
  compute(p);

  #pragma unroll
  for(int i=0;i<4;i++){
    #pragma unroll
    for(int j=0;j<4;j++){
      int cbase = bn + wc + j*16;
      unsigned long long b[4];
      #pragma unroll
      for(int reg=0; reg<4; reg++){
        float v = acc[i][j][reg];
        unsigned long long msk = __ballot(v > 0.f);
        b[reg] = msk;
        if (mr == 0){
          int r = bm + wr + i*16 + quad*4 + reg;
          unsigned int x = (unsigned int)(msk >> (quad*16)) & 0xFFFFu;
          x = (x | (x << 8)) & 0x00FF00FFu;
          x = (x | (x << 4)) & 0x0F0F0F0Fu;
          x = (x | (x << 2)) & 0x33333333u;
          x = (x | (x << 1)) & 0x55555555u;
          if (r >= cbase && r < cbase + 16) x += 1u << (2*(r - cbase));
          Cm[(size_t)r*256 + (cbase>>4)] = x;
        }
      }
      if (bx > by){
        unsigned int x = 0;
        #pragma unroll
        for(int reg=0; reg<4; reg++){
          unsigned long long t = (b[reg] >> mr) & 0x0001000100010001ULL;
          unsigned int f = (unsigned int)((t | (t>>15) | (t>>30) | (t>>45)) & 0xFULL);
          x |= ((f&1u) | ((f&2u)<<7) | ((f&4u)<<14) | ((f&8u)<<21)) << (2*reg);
        }
        if (quad == 0){
          int c = cbase + mr;
          Cm[(size_t)c*256 + ((bm + wr + i*16)>>4)] = x;
        }
      }
    }
  }
}

// ---------------------------------------------------------------------------
// GEMM body: C = A @ Bt^T, 128 x TN tile, NS-deep pipeline, swizzled LDS.
// EPI: 0 none | 1 relu->bf16 | 2 bf16 | 4 +bias+leaky f32
// EL:  0 none | 1/2 fused el/er partial rows via atomics (EL==2: head = bn>>9)
// ---------------------------------------------------------------------------
template<int EPI, int TN, int DUALA, int K, int LDA, int LDBT, int LDC,
         int K1, int LDA2, int WT, int NS, int EL>
__device__ __forceinline__
void gemm_body(const bf16* __restrict__ Ag, const bf16* __restrict__ Bt,
               void* __restrict__ Cv, const float* __restrict__ bias,
               const bf16* __restrict__ Ag2, bf16* __restrict__ Ct,
               const float* __restrict__ eA, const float* __restrict__ eB,
               float* __restrict__ eX, float* __restrict__ eY,
               unsigned int* SH, int bid)
{
  constexpr int NJ  = TN/32;
  constexpr int D   = 2 + TN/64;
  constexpr int NIT = K/32;
  unsigned int* As = SH;
  unsigned int* Bs = SH + NS*2048;
  const int tid = threadIdx.x;
  const int by = 4*(bid&7) + ((bid>>3)&3);
  const int bx = bid>>5;
  const int bm = by*128, bn = bx*TN;
  const int lane = tid&63, wid = tid>>6;
  const int wr = (wid>>1)*64, wc = (wid&1)*(TN/2);
  const int quad = lane>>4, mr = lane&15;
  const int L4 = lane>>2;
  const int lsw = (lane&3) ^ ((lane>>3)&3);
  const int qsw4 = ((quad ^ ((mr>>1)&3)) << 2);

  f32x4 acc[4][NJ];
  #pragma unroll
  for(int i=0;i<4;i++)
    #pragma unroll
    for(int j=0;j<NJ;j++) acc[i][j] = (f32x4){0.f,0.f,0.f,0.f};

  auto stage = [&](int kb, int p){
    #pragma unroll
    for(int c2=0; c2<2; c2++){
      int row = (wid*2+c2)*16 + L4;
      const bf16* ap;
      if (DUALA && kb >= K1) ap = Ag2 + (size_t)(bm+row)*LDA2 + (kb-K1);
      else                   ap = Ag  + (size_t)(bm+row)*LDA  + kb;
      gl2lds(ap + lsw*8, &As[p*2048 + (wid*2+c2)*256]);
    }
    #pragma unroll
    for(int c2=0; c2<TN/64; c2++){
      int row = (wid*(TN/64)+c2)*16 + L4;
      gl2lds(Bt + (size_t)(bn+row)*LDBT + kb + lsw*8,
             &Bs[p*(TN*16) + (wid*(TN/64)+c2)*256]);
    }
  };
  auto compute = [&](int p){
    short8 af[4], bfr[NJ];
    #pragma unroll
    for(int i=0;i<4;i++)
      af[i]  = *(const short8*)&As[p*2048 + (wr + i*16 + mr)*16 + qsw4];
    #pragma unroll
    for(int j=0;j<NJ;j++)
      bfr[j] = *(const short8*)&Bs[p*(TN*16) + (wc + j*16 + mr)*16 + qsw4];
    #pragma unroll
    for(int i=0;i<4;i++)
      #pragma unroll
      for(int j=0;j<NJ;j++)
        acc[i][j] = __builtin_amdgcn_mfma_f32_16x16x32_bf16(af[i], bfr[j], acc[i][j], 0,0,0);
  };

  #pragma unroll
  for(int s=0; s<NS-1; s++) stage(32*s, s);
  int p = 0;
  #pragma unroll 1
  for(int it=0; it<NIT-(NS-1); it++){
    waitvm<(NS-2)*D>();
    pipe_barrier();
    stage(32*(it+NS-1), (p+NS-1)&(NS-1));
    compute(p); p=(p+1)&(NS-1);
  }
  waitvm<0>(); pipe_barrier();
  #pragma unroll 1
  for(int r=0; r<NS-1; r++){ compute(p); p=(p+1)&(NS-1); }

  if (EPI==1 || EPI==2 || EPI==4){
    #pragma unroll
    for(int i=0;i<4;i++){
      #pragma unroll
      for(int j=0;j<NJ;j++){
        #pragma unroll
        for(int reg=0; reg<4; reg++){
          int r = bm + wr + i*16 + quad*4 + reg;
          int c = bn + wc + j*16 + mr;
          float v = acc[i][j][reg];
          if (EPI==1){ ((bf16*)Cv)[(size_t)r*LDC + c] = __float2bfloat16(fmaxf(v,0.f)); }
          if (EPI==2){ ((bf16*)Cv)[(size_t)r*LDC + c] = __float2bfloat16(v); }
          if (EPI==4){ float w = v + bias[c];
                       ((float*)Cv)[(size_t)r*LDC + c] = w > 0.f ? w : 0.01f*w; }
        }
      }
    }
  }

  if (EL){       // fused el/er partials (feat row . al/ar)
    float* elp = eX; float* erp = eY;
    if (EL==2){ int hh = bn >> 9; elp += hh*NN; erp += hh*NN; }
    #pragma unroll
    for(int i=0;i<4;i++){
      #pragma unroll
      for(int reg=0; reg<4; reg++){
        float pl = 0.f, pr = 0.f;
        #pragma unroll
        for(int j=0;j<NJ;j++){
          int c = bn + wc + j*16 + mr;
          float v = acc[i][j][reg];
          pl += v * eA[c];
          pr += v * eB[c];
        }
        #pragma unroll
        for(int s=1;s<16;s<<=1){ pl += __shfl_xor(pl, s); pr += __shfl_xor(pr, s); }
        if (mr == 0){
          int n = bm + wr + i*16 + quad*4 + reg;
          atomicAdd(&elp[n], pl*L2E);
          atomicAdd(&erp[n], pr*L2E);
        }
      }
    }
  }

  if (WT){   // transposed copy via padded LDS (stride 66 shorts), coalesced out
    __syncthreads();
    bf16* T = (bf16*)SH;
    #pragma unroll
    for(int i=0;i<4;i++)
      #pragma unroll
      for(int j=0;j<NJ;j++)
        #pragma unroll
        for(int reg=0; reg<4; reg++){
          int rl = wr + i*16 + quad*4 + reg;
          int cl = wc + j*16 + mr;
          T[rl*66 + cl] = __float2bfloat16(acc[i][j][reg]);
        }
    __syncthreads();
    #pragma unroll
    for(int w=0; w<TN/4; w++){
      int cl = wid*(TN/4) + w;
      unsigned int v = (unsigned int)(*(unsigned short*)&T[(2*lane)*66 + cl]) |
                       ((unsigned int)(*(unsigned short*)&T[(2*lane+1)*66 + cl]) << 16);
      *(unsigned int*)&Ct[(size_t)(bn+cl)*4096 + bm + 2*lane] = v;
    }
  }
}

// standalone GEMM kernel
template<int EPI, int TN, int DUALA, int K, int LDA, int LDBT, int LDC,
         int K1, int LDA2, int WT, int NS, int EL>
__global__ __launch_bounds__(256)
void gemm_k(const bf16* __restrict__ Ag, const bf16* __restrict__ Bt,
            void* __restrict__ Cv, const float* __restrict__ bias,
            const bf16* __restrict__ Ag2, bf16* __restrict__ Ct,
            const float* __restrict__ eA, const float* __restrict__ eB,
            float* __restrict__ eX, float* __restrict__ eY)
{
  __shared__ unsigned int SH[NS*2048 + NS*TN*16];
  gemm_body<EPI,TN,DUALA,K,LDA,LDBT,LDC,K1,LDA2,WT,NS,EL>(
      Ag, Bt, Cv, bias, Ag2, Ct, eA, eB, eX, eY, SH, blockIdx.x);
}

// merged dual-head aggregation: blocks 0..127 head0, 128..255 head1.
// TN=128 NS=4 (64 KB LDS): halves 32MB-P re-reads vs TN=64 (R9 A/B).
__global__ __launch_bounds__(256)
void agg2_k(const bf16* __restrict__ P, const bf16* __restrict__ P2,
            const bf16* __restrict__ featT, bf16* __restrict__ x2cat)
{
  __shared__ unsigned int SH[4*2048 + 4*128*16];
  int b = blockIdx.x;
  const bf16* A = (b < 128) ? P : P2;
  const bf16* B = (b < 128) ? featT : featT + (size_t)512*4096;
  bf16* C = (b < 128) ? x2cat : x2cat + 512;
  gemm_body<2,128,0,4096,4096,4096,1024,0,0,0,4,0>(
      A, B, C, nullptr, nullptr, nullptr, nullptr, nullptr, nullptr, nullptr,
      SH, b & 127);
}

// ---------------------------------------------------------------------------
// fused adjacency + feat1: blocks 0..527 adj tiles, 528..1039 feat1 GEMM
// (EPI=0: featT + fused el1/er1 only).
// ---------------------------------------------------------------------------
__global__ __launch_bounds__(256)
void adjfeat_k(const bf16* __restrict__ dfb, unsigned int* __restrict__ mult2,
               const bf16* __restrict__ W1tb, bf16* __restrict__ featT,
               const float* __restrict__ al1, const float* __restrict__ ar1,
               float* __restrict__ el1, float* __restrict__ er1)
{
  __shared__ unsigned int SH[12288];   // 48 KB union
  int b = blockIdx.x;
  if (b < 528){
    adj_body(dfb, mult2, SH, b);
  } else {
    gemm_body<0,64,0,2048,2048,2048,1024,0,0,1,4,1>(
        dfb, W1tb, nullptr, nullptr, nullptr, featT, al1, ar1, el1, er1,
        SH, b-528);
  }
}

// ---------------------------------------------------------------------------
// fused column softmax stats + alpha materialization (log2 space).
// ---------------------------------------------------------------------------
__global__ __launch_bounds__(256)
void colp_k(const float* __restrict__ el, const float* __restrict__ er,
            const unsigned int* __restrict__ mult2,
            float* __restrict__ cm, float* __restrict__ cinv,
            bf16* __restrict__ P, bf16* __restrict__ P2)
{
  __shared__ float sd[256];
  int d = blockIdx.x & 4095, hs = blockIdx.x >> 12, t = threadIdx.x;
  el += hs*NN; er += hs*NN; cm += hs*NN; cinv += hs*NN;
  float erd = er[d];
  unsigned int bits = mult2[(size_t)d*256 + t];
  float tv[16];
  float mx = -1e30f;
  const float* ep = el + t*16;
  #pragma unroll
  for(int h=0; h<4; h++){
    f32x4 ev = *(const f32x4*)(ep + h*4);
    #pragma unroll
    for(int q2=0;q2<4;q2++){
      int q = h*4 + q2;
      unsigned int mu = (bits >> (2*q)) & 3u;
      float x = ev[q2] + erd;
      x = fmaxf(x, 0.2f*x);
      if (mu == 2u) x += 1.0f;          // log2(2)
      tv[q] = mu ? x : -1e30f;
      mx = fmaxf(mx, tv[q]);
    }
  }
  #pragma unroll
  for(int s=32; s>0; s>>=1) mx = fmaxf(mx, __shfl_down(mx, s, 64));
  if ((t & 63) == 0) sd[t >> 6] = mx;
  __syncthreads();
  float M = fmaxf(fmaxf(sd[0], sd[1]), fmaxf(sd[2], sd[3]));
  __syncthreads();
  float sum = 0.f;
  #pragma unroll
  for(int q=0;q<16;q++) sum += (tv[q] > -1e29f) ? __builtin_exp2f(tv[q]-M) : 0.f;
  sum = br_sum(sum, sd);
  if(t==0){ cm[d] = M; cinv[d] = 1.f/sum; }
  bf16* Pd = (hs == 0) ? P : P2;
  if (Pd){
    float inv = 1.f/sum;
    unsigned int pk[8];
    #pragma unroll
    for(int h=0; h<4; h++){
      #pragma unroll
      for(int q2=0; q2<4; q2++){
        int q = h*4+q2;
        float v = (tv[q] > -1e29f) ? __builtin_exp2f(tv[q]-M)*inv : 0.f;
        bf16 hb = __float2bfloat16(v);
        unsigned short us = *(unsigned short*)&hb;
        if (q2 & 1) pk[h*2 + (q2>>1)] |= ((unsigned int)us << 16);
        else        pk[h*2 + (q2>>1)]  = (unsigned int)us;
      }
    }
    uint4* dst = (uint4*)(Pd + (size_t)d*4096 + t*16);
    dst[0] = *(uint4*)&pk[0];
    dst[1] = *(uint4*)&pk[4];
  }
}

// ---------------------------------------------------------------------------
// standalone alpha build (fallback path when workspace < 128 MB)
// ---------------------------------------------------------------------------
__global__ __launch_bounds__(256)
void pbuild_k(const float* __restrict__ el, const float* __restrict__ er,
              const float* __restrict__ cm, const float* __restrict__ cinv,
              const unsigned int* __restrict__ mult2, bf16* __restrict__ P)
{
  int d = blockIdx.x, t = threadIdx.x;
  const float erd = er[d], md = cm[d], invd = cinv[d];
  unsigned int bits = mult2[(size_t)d*256 + t];
  unsigned int pk[8];
  const float* ep = el + t*16;
  #pragma unroll
  for(int h=0; h<4; h++){
    f32x4 ev = *(const f32x4*)(ep + h*4);
    #pragma unroll
    for(int q2=0; q2<4; q2++){
      int q = h*4+q2;
      unsigned int mu = (bits >> (2*q)) & 3u;
      float x = ev[q2] + erd;
      x = fmaxf(x, 0.2f*x);
      float v = __builtin_exp2f(x + (mu>1u ? 1.0f : 0.0f) - md) * invd;
      v = mu ? v : 0.0f;
      bf16 hb = __float2bfloat16(v);
      unsigned short us = *(unsigned short*)&hb;
      if (q2 & 1) pk[h*2 + (q2>>1)] |= ((unsigned int)us << 16);
      else        pk[h*2 + (q2>>1)]  = (unsigned int)us;
    }
  }
  uint4* dst = (uint4*)(P + (size_t)d*4096 + t*16);
  dst[0] = *(uint4*)&pk[0];
  dst[1] = *(uint4*)&pk[4];
}

// ---------------------------------------------------------------------------
// classifier 1 (logits2 folded into prep_all_k); f32x4 loads
// ---------------------------------------------------------------------------
__global__ __launch_bounds__(256)
void cls2_k(const float* __restrict__ x3, const float* __restrict__ c1w,
            const float* __restrict__ c1b, float* __restrict__ out)
{
  __shared__ float sd[256];
  int n = blockIdx.x, t = threadIdx.x, k0 = t*4;
  f32x4 xv = *(const f32x4*)(x3 + (size_t)n*1024 + k0);
  float acc[10] = {};
  #pragma unroll
  for(int q=0;q<4;q++){
    #pragma unroll
    for(int c=0;c<10;c++) acc[c] += xv[q] * c1w[(k0+q)*10 + c];
  }
  for(int c=0;c<10;c++){
    float r = br_sum(acc[c], sd);
    if(t==0) out[n*10 + c] = r + c1b[c];
  }
}

// ---------------------------------------------------------------------------
extern "C" void kernel_launch(void* const* d_in, const int* in_sizes, int n_in,
                              void* d_out, int out_size, void* d_ws, size_t ws_size,
                              hipStream_t stream) {
  (void)in_sizes; (void)n_in; (void)out_size;
  const float* df  = (const float*)d_in[0];
  const float* W1  = (const float*)d_in[1];
  const float* al1 = (const float*)d_in[2];
  const float* ar1 = (const float*)d_in[3];
  const float* W2  = (const float*)d_in[4];
  const float* al2 = (const float*)d_in[5];
  const float* ar2 = (const float*)d_in[6];
  const float* lw  = (const float*)d_in[7];
  const float* lb  = (const float*)d_in[8];
  const float* c1w = (const float*)d_in[9];
  const float* c1b = (const float*)d_in[10];
  const float* c2w = (const float*)d_in[11];
  const float* c2b = (const float*)d_in[12];
  float* out = (float*)d_out;

  char* Wp = (char*)d_ws;
  bf16* W1tb  = (bf16*)(Wp);                                // 4 MB, dead after feat1
  bf16* W2tb  = (bf16*)(Wp + ( 4u<<20));                    // 2 MB
  bf16* lwcat = (bf16*)(Wp + ( 6u<<20));                    // 6 MB [1024][3072]
  unsigned int* mult2 = (unsigned int*)(Wp + (12u<<20));    // 4 MB packed adj
  bf16* dfb   = (bf16*)(Wp + (16u<<20));                    // 16 MB [4096][2048]
  float* SB2  = (float*)(Wp + (32u<<20));                   // el2/er2/m2/i2 (128 KB)
  float* x3   = (float*)(Wp + (32u<<20));                   // 16 MB (over SB2, written after)
  bf16* featT = (bf16*)(Wp + (48u<<20));                    // 8 MB [1024][4096]
  float* SA   = (float*)(Wp + (56u<<20));                   // el1/er1/m1/i1 (64 KB)
  bf16* x1b   = (bf16*)(Wp + (56u<<20));                    // 8 MB (over SA, after colp1)
  bf16* x2cat = (bf16*)(Wp + (56u<<20));                    // 8 MB (x1b dead)
  bf16* P     = (bf16*)(Wp + (64u<<20));                    // 32 MB alpha h0
  bf16* P2    = (bf16*)(Wp + (96u<<20));                    // 32 MB alpha h1 (if ws allows)
  const bool bigws = ws_size >= ((size_t)128 << 20);
  float *el1 = SA,        *er1 = SA + 4096;
  float *m1  = SA + 8192, *i1  = SA + 12288;
  float *el2 = SB2,           *er2 = SB2 + 8192;            // [2N] each
  float *m2  = SB2 + 16384,   *i2  = SB2 + 24576;

  // 0) prep: df convert + logits2, transposes, el/er zeroing
  prep_all_k<<<5520,256,0,stream>>>(df, W1, W2, lw, dfb, W1tb, W2tb, lwcat,
                                    c2w, c2b, out + NN*10, SA, SB2);

  // 1+2) adjacency (528) + feat1 GEMM (512): featT + fused el1/er1
  adjfeat_k<<<1040,256,0,stream>>>(dfb, mult2, W1tb, featT, al1, ar1, el1, er1);

  // 3) layer-1 stats + alpha (P)
  colp_k<<<4096,256,0,stream>>>(el1, er1, mult2, m1, i1, P, nullptr);

  // 4) x1 = relu(P @ feat1)  TN=128 NS=4 (64 KB LDS)
  gemm_k<1,128,0,4096,4096,4096,1024,0,0,0,4,0><<<256,256,0,stream>>>(
      P, featT, x1b, nullptr, nullptr, nullptr, nullptr, nullptr, nullptr, nullptr);

  // 5) feat2: featT + fused el2/er2 (no row-major C), TN=128 NS=4
  gemm_k<0,128,0,1024,1024,1024,1024,0,0,1,4,2><<<256,256,0,stream>>>(
      x1b, W2tb, nullptr, nullptr, nullptr, featT, al2, ar2, el2, er2);

  // 6) layer-2 stats + alpha (P / P2)
  colp_k<<<8192,256,0,stream>>>(el2, er2, mult2, m2, i2, P, bigws ? P2 : nullptr);

  if (bigws){
    agg2_k<<<256,256,0,stream>>>(P, P2, featT, x2cat);
  } else {
    gemm_k<2,64,0,4096,4096,4096,1024,0,0,0,4,0><<<512,256,0,stream>>>(
        P, featT, x2cat, nullptr, nullptr, nullptr, nullptr, nullptr, nullptr, nullptr);
    pbuild_k<<<4096,256,0,stream>>>(el2+NN, er2+NN, m2+NN, i2+NN, mult2, P);
    gemm_k<2,64,0,4096,4096,4096,1024,0,0,0,4,0><<<512,256,0,stream>>>(
        P, featT + (size_t)512*4096, x2cat + 512, nullptr, nullptr, nullptr,
        nullptr, nullptr, nullptr, nullptr);
  }

  // 7) x3 = leaky([df | x2] @ lin1_w + b), dual-A K=3072, TN=128 NS=4
  gemm_k<4,128,1,3072,2048,3072,1024,2048,1024,0,4,0><<<256,256,0,stream>>>(
      dfb, lwcat, x3, lb, x2cat, nullptr, nullptr, nullptr, nullptr, nullptr);

  // 8) classifier 1 -> f32 out
  cls2_k<<<4096,256,0,stream>>>(x3, c1w, c1b, out);
}